// Round 11
// baseline (426.521 us; speedup 1.0000x reference)
//
#include <hip/hip_runtime.h>
#include <hip/hip_bf16.h>
#include <math.h>

#define B 16
#define N 512
#define L 512
#define DIM 10
#define DM 128
#define H 8
#define DK 16
#define DFF 512
#define LG 3
#define LO 3
#define NEGV -9.0e15f
#define RF 16     // rows per block (ffn/qkv/oproj)
#define AQR 64    // q-rows per attn block
#define KT 64     // keys per attn tile
#define NT (L / KT)

__device__ __forceinline__ float wave_reduce_sum(float v) {
    #pragma unroll
    for (int o = 32; o > 0; o >>= 1) v += __shfl_down(v, o, 64);
    return v;
}

__device__ __forceinline__ float dot16(float4 q0, float4 q1, float4 q2, float4 q3,
                                       float4 k0, float4 k1, float4 k2, float4 k3) {
    return q0.x*k0.x + q0.y*k0.y + q0.z*k0.z + q0.w*k0.w
         + q1.x*k1.x + q1.y*k1.y + q1.z*k1.z + q1.w*k1.w
         + q2.x*k2.x + q2.y*k2.y + q2.z*k2.z + q2.w*k2.w
         + q3.x*k3.x + q3.y*k3.y + q3.z*k3.z + q3.w*k3.w;
}

// ---------------- GNN ----------------

__global__ void k_embed_fp(const int* __restrict__ fing, const float* __restrict__ emb_fp,
                           float* __restrict__ xs) {
    int idx = blockIdx.x * blockDim.x + threadIdx.x;
    if (idx >= B * N * DIM) return;
    int d = idx % DIM;
    int bn = idx / DIM;
    xs[idx] = emb_fp[fing[bn] * DIM + d];
}

__global__ void k_gnn_h(const float* __restrict__ xs, const float* __restrict__ fp_mask,
                        const float* __restrict__ Wg, const float* __restrict__ bg,
                        const float* __restrict__ aatt,
                        float* __restrict__ h, float* __restrict__ s1, float* __restrict__ s2) {
    int bn = blockIdx.x * blockDim.x + threadIdx.x;
    if (bn >= B * N) return;
    float x[DIM];
    #pragma unroll
    for (int d = 0; d < DIM; d++) x[d] = xs[bn * DIM + d];
    float m = fp_mask[bn];
    float a1 = 0.f, a2 = 0.f;
    #pragma unroll
    for (int j = 0; j < DIM; j++) {
        float acc = bg[j];
        #pragma unroll
        for (int d = 0; d < DIM; d++) acc += x[d] * Wg[d * DIM + j];
        acc = fmaxf(acc, 0.f) * m;
        h[bn * DIM + j] = acc;
        a1 += acc * aatt[j];
        a2 += acc * aatt[DIM + j];
    }
    s1[bn] = a1;
    s2[bn] = a2;
}

// 16 lane-groups of 16 lanes; each group owns one row. grid = B*(N/16), 256 thr.
__global__ void k_gnn_att(const float* __restrict__ h, const float* __restrict__ s1,
                          const float* __restrict__ s2, const int* __restrict__ adj,
                          float* __restrict__ xs) {
    int b  = blockIdx.x / (N / 16);
    int rg = blockIdx.x % (N / 16);
    int t = threadIdx.x;
    int g  = t >> 4;   // group 0..15
    int ll = t & 15;   // lane in group
    int i = rg * 16 + g;

    __shared__ float h_s[N * DIM];   // 20KB
    __shared__ float s2_s[N];        // 2KB

    const float* hb = h + (long)b * N * DIM;
    for (int idx = t; idx < N * DIM; idx += 256) h_s[idx] = hb[idx];
    for (int j = t; j < N; j += 256) s2_s[j] = s2[b * N + j];
    __syncthreads();

    float s1v = s1[b * N + i];
    const int* adjrow = adj + ((long)b * N + i) * N;

    float e[32];
    #pragma unroll
    for (int c = 0; c < 32; c++) {
        int j = c * 16 + ll;
        float xsc = s1v + s2_s[j];
        xsc = xsc > 0.f ? xsc : 0.01f * xsc;
        e[c] = (adjrow[j] > 0) ? xsc : NEGV;
    }
    float m = e[0];
    #pragma unroll
    for (int c = 1; c < 32; c++) m = fmaxf(m, e[c]);
    #pragma unroll
    for (int off = 1; off < 16; off <<= 1) m = fmaxf(m, __shfl_xor(m, off, 64));

    float sum = 0.f;
    float a[DIM];
    #pragma unroll
    for (int d = 0; d < DIM; d++) a[d] = 0.f;
    #pragma unroll
    for (int c = 0; c < 32; c++) {
        float p = expf(e[c] - m);
        sum += p;
        int j = c * 16 + ll;
        #pragma unroll
        for (int d = 0; d < DIM; d++) a[d] += p * h_s[j * DIM + d];
    }
    #pragma unroll
    for (int off = 1; off < 16; off <<= 1) {
        sum += __shfl_xor(sum, off, 64);
        #pragma unroll
        for (int d = 0; d < DIM; d++) a[d] += __shfl_xor(a[d], off, 64);
    }
    if (ll < DIM) {
        float av = a[0];
        if (ll == 1) av = a[1]; else if (ll == 2) av = a[2]; else if (ll == 3) av = a[3];
        else if (ll == 4) av = a[4]; else if (ll == 5) av = a[5]; else if (ll == 6) av = a[6];
        else if (ll == 7) av = a[7]; else if (ll == 8) av = a[8]; else if (ll == 9) av = a[9];
        xs[((long)b * N + i) * DIM + ll] += av / sum;
    }
}

__global__ void k_compound(const float* __restrict__ xs, const float* __restrict__ fp_mask,
                           const float* __restrict__ Watt, const float* __restrict__ batt,
                           float* __restrict__ compound, float* __restrict__ hc) {
    int b = blockIdx.x;
    int t = threadIdx.x;  // 256
    int wid = t >> 6, lane = t & 63;
    float lacc[DIM];
    #pragma unroll
    for (int d = 0; d < DIM; d++) lacc[d] = 0.f;
    for (int n = t; n < N; n += 256) {
        float m = fp_mask[b * N + n];
        #pragma unroll
        for (int d = 0; d < DIM; d++) lacc[d] += xs[((long)b * N + n) * DIM + d] * m;
    }
    __shared__ float red[4][DIM];
    __shared__ float comp_s[DIM];
    #pragma unroll
    for (int d = 0; d < DIM; d++) lacc[d] = wave_reduce_sum(lacc[d]);
    if (lane == 0) {
        #pragma unroll
        for (int d = 0; d < DIM; d++) red[wid][d] = lacc[d];
    }
    __syncthreads();
    if (t < DIM) {
        float c = (red[0][t] + red[1][t] + red[2][t] + red[3][t]) / (float)N;
        compound[b * DIM + t] = c;
        comp_s[t] = c;
    }
    __syncthreads();
    if (t < DIM) {
        float acc = batt[t];
        #pragma unroll
        for (int e = 0; e < DIM; e++) acc += comp_s[e] * Watt[e * DIM + t];
        hc[b * DIM + t] = fmaxf(acc, 0.f);
    }
}

// ---------------- Transformer ----------------

__global__ void k_pe(float* __restrict__ pe) {
    int idx = blockIdx.x * blockDim.x + threadIdx.x;
    if (idx >= L * DM) return;
    int d = idx % DM, l = idx / DM;
    int k = d >> 1;
    double div = exp((double)(2 * k) * (-log(10000.0) / (double)DM));
    double ang = (double)l * div;
    pe[idx] = (d & 1) ? (float)cos(ang) : (float)sin(ang);
}

__global__ void k_embed_word(const int* __restrict__ words, const float* __restrict__ emb,
                             const float* __restrict__ pe, float* __restrict__ x) {
    long idx = (long)blockIdx.x * blockDim.x + threadIdx.x;
    if (idx >= (long)B * L * DM) return;
    int d = idx % DM;
    long bl = idx / DM;
    int l = (int)(bl % L);
    x[idx] = emb[(long)words[bl] * DM + d] * sqrtf(128.0f) + pe[l * DM + d];
}

__global__ void k_layernorm(const float* __restrict__ x, const float* __restrict__ g,
                            const float* __restrict__ bb, float* __restrict__ out) {
    int row = blockIdx.x;
    int t = threadIdx.x;  // 128
    int wid = t >> 6, lane = t & 63;
    float v = x[(long)row * DM + t];
    float s = wave_reduce_sum(v);
    __shared__ float r2[2], r3[2];
    if (lane == 0) r2[wid] = s;
    __syncthreads();
    float mean = (r2[0] + r2[1]) / (float)DM;
    float dv = v - mean;
    float q = wave_reduce_sum(dv * dv);
    if (lane == 0) r3[wid] = q;
    __syncthreads();
    float sd = sqrtf((r3[0] + r3[1]) / (float)(DM - 1)) + 1e-6f;
    out[(long)row * DM + t] = g[t] * dv / sd + bb[t];
}

// 16 rows per block, 384 threads: thread = (proj, out-col)
__global__ void k_qkv(const float* __restrict__ xn,
                      const float* __restrict__ Wq, const float* __restrict__ bq,
                      const float* __restrict__ Wk, const float* __restrict__ bk,
                      const float* __restrict__ Wv, const float* __restrict__ bv,
                      float* __restrict__ q, float* __restrict__ k, float* __restrict__ v) {
    long row0 = (long)blockIdx.x * RF;
    int t = threadIdx.x;  // 384
    __shared__ float xs_s[RF * DM];
    for (int i = t; i < RF * DM; i += 384) xs_s[i] = xn[row0 * DM + i];
    __syncthreads();
    int proj = t / DM;
    int j = t % DM;
    const float* W    = proj == 0 ? Wq : (proj == 1 ? Wk : Wv);
    const float* bias = proj == 0 ? bq : (proj == 1 ? bk : bv);
    float* out        = proj == 0 ? q  : (proj == 1 ? k  : v);
    float acc[RF];
    #pragma unroll
    for (int r = 0; r < RF; r++) acc[r] = bias[j];
    for (int d = 0; d < DM; d++) {
        float w = W[d * DM + j];
        #pragma unroll
        for (int r = 0; r < RF; r++) acc[r] += xs_s[r * DM + d] * w;
    }
    #pragma unroll
    for (int r = 0; r < RF; r++) {
        long row = row0 + r;
        int b = (int)(row / L), l = (int)(row % L);
        out[(((long)b * H + j / DK) * L + l) * DK + (j % DK)] = acc[r];
    }
}

// Tiled flash attention, rows=1. grid = B*H*(L/64), 512 threads (8 waves).
// Thread = (q-row qg = t>>3, 8 keys kg = t&7). Q frag (16) + O acc (16) in
// regs (~34 persistent -> no spill at the observed 64-VGPR compiler cap).
// K/V double-buffered in LDS; staging is reg->LDS with PRE-SWIZZLED global
// source (chunk ^= (key>>3)&3, both-sides rule): writes 64-distinct-16B
// coalesced, reads <=2-way bank aliasing (free). Scores fully lane-local
// (no per-key shuffles); one butterfly merge across the 8 kg lanes at end.
__global__ void __launch_bounds__(512, 1)
k_attn(const float* __restrict__ q, const float* __restrict__ k,
       const float* __restrict__ v, const float* __restrict__ wmask,
       float* __restrict__ attnout) {
    int blk = blockIdx.x;
    int qc = blk % (L / AQR);
    int bh = blk / (L / AQR);
    int b = bh / H, hh = bh % H;
    int t = threadIdx.x;   // 512
    int qg = t >> 3;       // q-row 0..63
    int kg = t & 7;        // key group (8 keys per tile)
    int l = qc * AQR + qg;

    __shared__ float kbuf[2][KT * DK];   // 8KB
    __shared__ float vbuf[2][KT * DK];   // 8KB
    __shared__ float madd[2][KT];        // additive mask 0 / -1e9

    const float4* kb4 = (const float4*)(k + (long)bh * L * DK);
    const float4* vb4 = (const float4*)(v + (long)bh * L * DK);
    const float*  wm  = wmask + (long)b * L;

    // Q row (16 dims), pre-scaled
    const float4* qp = (const float4*)(q + ((long)bh * L + l) * DK);
    float4 q0 = qp[0], q1 = qp[1], q2 = qp[2], q3 = qp[3];
    q0.x*=0.25f;q0.y*=0.25f;q0.z*=0.25f;q0.w*=0.25f;
    q1.x*=0.25f;q1.y*=0.25f;q1.z*=0.25f;q1.w*=0.25f;
    q2.x*=0.25f;q2.y*=0.25f;q2.z*=0.25f;q2.w*=0.25f;
    q3.x*=0.25f;q3.y*=0.25f;q3.z*=0.25f;q3.w*=0.25f;

    // staging role: threads 0-255 stage K, 256-511 stage V; 1 float4 each
    int si = t & 255;
    int skey = si >> 2, sc = si & 3;
    int gch = sc ^ ((skey >> 3) & 3);          // pre-swizzled source chunk
    const float4* gsrc = (t < 256) ? kb4 : vb4;
    long gidx = (long)skey * 4 + gch;

    // prologue: stage tile 0
    {
        float4 r = gsrc[gidx];
        float* dst = (t < 256) ? &kbuf[0][0] : &vbuf[0][0];
        ((float4*)dst)[si] = r;
        if (t < KT) madd[0][t] = (wm[t] > 0.f) ? 0.f : -1e9f;
    }
    __syncthreads();

    float m = -1e30f, ss = 0.f;
    float4 a0 = make_float4(0,0,0,0), a1 = a0, a2 = a0, a3 = a0;
    int swz = kg & 3;

    int cur = 0;
    for (int tt = 0; tt < NT; tt++) {
        // T14: issue next tile's loads early (consumed after compute)
        float4 pre;
        float mpre = 1.f;
        if (tt < NT - 1) {
            pre = gsrc[(long)(tt + 1) * KT * 4 + gidx];
            if (t < KT) mpre = wm[(tt + 1) * KT + t];
        }

        // ---- QK^T: 8 lane-local full dots ----
        float s[8];
        #pragma unroll
        for (int kk = 0; kk < 8; kk++) {
            const float4* kp = (const float4*)&kbuf[cur][(kg * 8 + kk) * DK];
            float4 k0 = kp[0 ^ swz], k1 = kp[1 ^ swz], k2 = kp[2 ^ swz], k3 = kp[3 ^ swz];
            s[kk] = dot16(q0, q1, q2, q3, k0, k1, k2, k3);
        }
        {
            const float4* mp = (const float4*)&madd[cur][kg * 8];
            float4 ma = mp[0], mb_ = mp[1];
            s[0] += ma.x;  s[1] += ma.y;  s[2] += ma.z;  s[3] += ma.w;
            s[4] += mb_.x; s[5] += mb_.y; s[6] += mb_.z; s[7] += mb_.w;
        }

        // ---- lane-local online softmax update ----
        float cm = fmaxf(fmaxf(fmaxf(s[0], s[1]), fmaxf(s[2], s[3])),
                         fmaxf(fmaxf(s[4], s[5]), fmaxf(s[6], s[7])));
        float mn = fmaxf(m, cm);
        float scale = __expf(m - mn);
        m = mn;
        float pls = 0.f;
        #pragma unroll
        for (int kk = 0; kk < 8; kk++) { s[kk] = __expf(s[kk] - mn); pls += s[kk]; }
        ss = ss * scale + pls;
        a0.x*=scale;a0.y*=scale;a0.z*=scale;a0.w*=scale;
        a1.x*=scale;a1.y*=scale;a1.z*=scale;a1.w*=scale;
        a2.x*=scale;a2.y*=scale;a2.z*=scale;a2.w*=scale;
        a3.x*=scale;a3.y*=scale;a3.z*=scale;a3.w*=scale;

        // ---- PV ----
        #pragma unroll
        for (int kk = 0; kk < 8; kk++) {
            const float4* vp = (const float4*)&vbuf[cur][(kg * 8 + kk) * DK];
            float4 v0 = vp[0 ^ swz], v1 = vp[1 ^ swz], v2 = vp[2 ^ swz], v3 = vp[3 ^ swz];
            float p = s[kk];
            a0.x += p*v0.x; a0.y += p*v0.y; a0.z += p*v0.z; a0.w += p*v0.w;
            a1.x += p*v1.x; a1.y += p*v1.y; a1.z += p*v1.z; a1.w += p*v1.w;
            a2.x += p*v2.x; a2.y += p*v2.y; a2.z += p*v2.z; a2.w += p*v2.w;
            a3.x += p*v3.x; a3.y += p*v3.y; a3.z += p*v3.z; a3.w += p*v3.w;
        }

        // ---- write prefetched data into the other buffer, flip ----
        if (tt < NT - 1) {
            float* dst = (t < 256) ? &kbuf[cur ^ 1][0] : &vbuf[cur ^ 1][0];
            ((float4*)dst)[si] = pre;
            if (t < KT) madd[cur ^ 1][t] = (mpre > 0.f) ? 0.f : -1e9f;
        }
        __syncthreads();
        cur ^= 1;
    }

    // ---- butterfly merge across the 8 kg lanes (same row) ----
    #pragma unroll
    for (int off = 1; off <= 4; off <<= 1) {
        float m2  = __shfl_xor(m, off, 64);
        float ss2 = __shfl_xor(ss, off, 64);
        float mn = fmaxf(m, m2);
        float ea = __expf(m - mn), eb = __expf(m2 - mn);
        ss = ss * ea + ss2 * eb;
        #define MRG(f) { float o_ = __shfl_xor(f, off, 64); f = f * ea + o_ * eb; }
        MRG(a0.x) MRG(a0.y) MRG(a0.z) MRG(a0.w)
        MRG(a1.x) MRG(a1.y) MRG(a1.z) MRG(a1.w)
        MRG(a2.x) MRG(a2.y) MRG(a2.z) MRG(a2.w)
        MRG(a3.x) MRG(a3.y) MRG(a3.z) MRG(a3.w)
        #undef MRG
        m = mn;
    }

    if (kg < 4) {
        float4 ov = (kg == 0) ? a0 : (kg == 1) ? a1 : (kg == 2) ? a2 : a3;
        float inv = 1.f / ss;
        float4* outp = (float4*)(attnout + ((long)b * L + l) * DM + hh * DK);
        outp[kg] = make_float4(ov.x * inv, ov.y * inv, ov.z * inv, ov.w * inv);
    }
}

// x += attnout @ Wo + bo ; 16 rows/block, 128 threads
__global__ void k_oproj(const float* __restrict__ attnout, const float* __restrict__ Wo,
                        const float* __restrict__ bo, float* __restrict__ x) {
    long row0 = (long)blockIdx.x * RF;
    int t = threadIdx.x;  // 128
    __shared__ float a_s[RF * DM];
    for (int i = t; i < RF * DM; i += 128) a_s[i] = attnout[row0 * DM + i];
    __syncthreads();
    float acc[RF];
    #pragma unroll
    for (int r = 0; r < RF; r++) acc[r] = bo[t];
    for (int d = 0; d < DM; d++) {
        float w = Wo[d * DM + t];
        #pragma unroll
        for (int r = 0; r < RF; r++) acc[r] += a_s[r * DM + d] * w;
    }
    #pragma unroll
    for (int r = 0; r < RF; r++) x[(row0 + r) * DM + t] += acc[r];
}

// fused FFN: x += relu(xn@W1+b1)@W2+b2 ; 16 rows/block, 512 threads
__global__ void k_ffn(const float* __restrict__ xn, const float* __restrict__ W1,
                      const float* __restrict__ b1, const float* __restrict__ W2,
                      const float* __restrict__ b2, float* __restrict__ x) {
    long row0 = (long)blockIdx.x * RF;
    int t = threadIdx.x;  // 512
    __shared__ float xs_s[RF * DM];    // 8KB
    __shared__ float h_s[RF * DFF];    // 32KB
    for (int i = t; i < RF * DM; i += 512) xs_s[i] = xn[row0 * DM + i];
    __syncthreads();
    {
        float acc[RF];
        #pragma unroll
        for (int r = 0; r < RF; r++) acc[r] = b1[t];
        for (int d = 0; d < DM; d++) {
            float w = W1[d * DFF + t];
            #pragma unroll
            for (int r = 0; r < RF; r++) acc[r] += xs_s[r * DM + d] * w;
        }
        #pragma unroll
        for (int r = 0; r < RF; r++) h_s[r * DFF + t] = fmaxf(acc[r], 0.f);
    }
    __syncthreads();
    int col = t & 127, rq = t >> 7;   // rq uniform per wave
    float acc2[4];
    #pragma unroll
    for (int rr = 0; rr < 4; rr++) acc2[rr] = b2[col];
    for (int f = 0; f < DFF; f++) {
        float w = W2[f * DM + col];
        #pragma unroll
        for (int rr = 0; rr < 4; rr++) acc2[rr] += h_s[(rq * 4 + rr) * DFF + f] * w;
    }
    #pragma unroll
    for (int rr = 0; rr < 4; rr++) x[(row0 + rq * 4 + rr) * DM + col] += acc2[rr];
}

// lnf -> relu -> Wtout -> Watt/relu -> hp ; per row, 128 threads
__global__ void k_lnf_hp(const float* __restrict__ x, const float* __restrict__ g,
                         const float* __restrict__ bb, const float* __restrict__ Wtout,
                         const float* __restrict__ btout, const float* __restrict__ Watt,
                         const float* __restrict__ batt, float* __restrict__ hp) {
    int row = blockIdx.x;
    int t = threadIdx.x;  // 128
    int wid = t >> 6, lane = t & 63;
    float v = x[(long)row * DM + t];
    float s = wave_reduce_sum(v);
    __shared__ float r2[2], r3[2];
    if (lane == 0) r2[wid] = s;
    __syncthreads();
    float mean = (r2[0] + r2[1]) / (float)DM;
    float dv = v - mean;
    float qq = wave_reduce_sum(dv * dv);
    if (lane == 0) r3[wid] = qq;
    __syncthreads();
    float sd = sqrtf((r3[0] + r3[1]) / (float)(DM - 1)) + 1e-6f;
    float xnv = g[t] * dv / sd + bb[t];
    __shared__ float rrelu[DM];
    rrelu[t] = fmaxf(xnv, 0.f);
    __syncthreads();
    __shared__ float wv_s[DIM];
    if (t < DIM) {
        float acc = btout[t];
        for (int d = 0; d < DM; d++) acc += rrelu[d] * Wtout[d * DIM + t];
        wv_s[t] = acc;
    }
    __syncthreads();
    if (t < DIM) {
        float acc = batt[t];
        #pragma unroll
        for (int e = 0; e < DIM; e++) acc += wv_s[e] * Watt[e * DIM + t];
        hp[(long)row * DIM + t] = fmaxf(acc, 0.f);
    }
}

// final: w = tanh(hc . hp_l) ; protein = mean(w * hp) ; 3-layer MLP ; output.
__global__ void k_final(const float* __restrict__ hp, const float* __restrict__ hc,
                        const float* __restrict__ compound, const float* __restrict__ Wout,
                        const float* __restrict__ bout, const float* __restrict__ Wint,
                        const float* __restrict__ bint, float* __restrict__ out) {
    int b = blockIdx.x;
    int t = threadIdx.x;  // 256
    int wid = t >> 6, lane = t & 63;

    __shared__ float wout_s[LO * 2 * DIM * 2 * DIM];  // 1200 floats
    __shared__ float bout_s[LO * 2 * DIM];
    __shared__ float wint_s[2 * DIM * 2];
    __shared__ float bint_s[2];
    __shared__ float hc_s[DIM];
    __shared__ float red[4][DIM];
    __shared__ float cat_s[2 * DIM];
    __shared__ float tmp_s[2 * DIM];

    for (int i = t; i < LO * 2 * DIM * 2 * DIM; i += 256) wout_s[i] = Wout[i];
    for (int i = t; i < LO * 2 * DIM; i += 256) bout_s[i] = bout[i];
    for (int i = t; i < 2 * DIM * 2; i += 256) wint_s[i] = Wint[i];
    if (t < 2) bint_s[t] = bint[t];
    if (t < DIM) hc_s[t] = hc[b * DIM + t];
    __syncthreads();

    float lacc[DIM];
    #pragma unroll
    for (int e = 0; e < DIM; e++) lacc[e] = 0.f;
    for (int l = t; l < L; l += 256) {
        const float* hpl = hp + ((long)b * L + l) * DIM;
        float hv[DIM];
        float dot = 0.f;
        #pragma unroll
        for (int e = 0; e < DIM; e++) { hv[e] = hpl[e]; dot += hc_s[e] * hv[e]; }
        float w = tanhf(dot);
        #pragma unroll
        for (int e = 0; e < DIM; e++) lacc[e] += w * hv[e];
    }
    #pragma unroll
    for (int e = 0; e < DIM; e++) lacc[e] = wave_reduce_sum(lacc[e]);
    if (lane == 0) {
        #pragma unroll
        for (int e = 0; e < DIM; e++) red[wid][e] = lacc[e];
    }
    __syncthreads();
    if (t < DIM) {
        cat_s[t] = compound[b * DIM + t];
        cat_s[DIM + t] = (red[0][t] + red[1][t] + red[2][t] + red[3][t]) / (float)L;
    }
    __syncthreads();

    for (int j = 0; j < LO; j++) {
        float acc = 0.f;
        if (t < 2 * DIM) {
            acc = bout_s[j * 2 * DIM + t];
            #pragma unroll
            for (int e = 0; e < 2 * DIM; e++)
                acc += cat_s[e] * wout_s[j * 2 * DIM * 2 * DIM + e * 2 * DIM + t];
            acc = fmaxf(acc, 0.f);
            tmp_s[t] = acc;
        }
        __syncthreads();
        if (t < 2 * DIM) cat_s[t] = tmp_s[t];
        __syncthreads();
    }
    if (t < 2) {
        float o = bint_s[t];
        #pragma unroll
        for (int e = 0; e < 2 * DIM; e++) o += cat_s[e] * wint_s[e * 2 + t];
        out[b * 2 + t] = o;
    }
}

extern "C" void kernel_launch(void* const* d_in, const int* in_sizes, int n_in,
                              void* d_out, int out_size, void* d_ws, size_t ws_size,
                              hipStream_t stream) {
    (void)in_sizes; (void)n_in; (void)out_size; (void)ws_size;
    const int*   fingerprints = (const int*)d_in[0];
    const float* fp_mask      = (const float*)d_in[1];
    const int*   adjacency    = (const int*)d_in[2];
    const int*   words        = (const int*)d_in[3];
    const float* words_mask   = (const float*)d_in[4];
    const float* emb_fp       = (const float*)d_in[5];
    const float* emb_word     = (const float*)d_in[6];
    const float* Wg   = (const float*)d_in[7];
    const float* bg   = (const float*)d_in[8];
    const float* attn_a = (const float*)d_in[9];
    const float* Wq = (const float*)d_in[10];
    const float* bq = (const float*)d_in[11];
    const float* Wk = (const float*)d_in[12];
    const float* bk = (const float*)d_in[13];
    const float* Wv = (const float*)d_in[14];
    const float* bv = (const float*)d_in[15];
    const float* Wo = (const float*)d_in[16];
    const float* bo = (const float*)d_in[17];
    const float* ln1_g = (const float*)d_in[18];
    const float* ln1_b = (const float*)d_in[19];
    const float* ln2_g = (const float*)d_in[20];
    const float* ln2_b = (const float*)d_in[21];
    const float* lnf_g = (const float*)d_in[22];
    const float* lnf_b = (const float*)d_in[23];
    const float* W1 = (const float*)d_in[24];
    const float* b1 = (const float*)d_in[25];
    const float* W2 = (const float*)d_in[26];
    const float* b2 = (const float*)d_in[27];
    const float* Wtout = (const float*)d_in[28];
    const float* btout = (const float*)d_in[29];
    const float* Watt  = (const float*)d_in[30];
    const float* batt  = (const float*)d_in[31];
    const float* Wout  = (const float*)d_in[32];
    const float* bout  = (const float*)d_in[33];
    const float* Wint  = (const float*)d_in[34];
    const float* bint  = (const float*)d_in[35];
    float* out = (float*)d_out;

    float* w = (float*)d_ws;
    float* xs = w;        w += B * N * DIM;
    float* h  = w;        w += B * N * DIM;
    float* s1 = w;        w += B * N;
    float* s2 = w;        w += B * N;
    float* compound = w;  w += B * DIM;
    float* hc = w;        w += B * DIM;
    float* pe = w;        w += L * DM;
    float* x  = w;        w += (long)B * L * DM;
    float* xn = w;        w += (long)B * L * DM;
    float* qb = w;        w += (long)B * H * L * DK;
    float* kb = w;        w += (long)B * H * L * DK;
    float* vb = w;        w += (long)B * H * L * DK;
    float* attnout = w;   w += (long)B * L * DM;
    float* hp = w;        w += (long)B * L * DIM;

    // ---- GNN ----
    k_embed_fp<<<(B * N * DIM + 255) / 256, 256, 0, stream>>>(fingerprints, emb_fp, xs);
    for (int i = 0; i < LG; i++) {
        k_gnn_h<<<(B * N + 255) / 256, 256, 0, stream>>>(
            xs, fp_mask, Wg + i * DIM * DIM, bg + i * DIM, attn_a + i * 2 * DIM, h, s1, s2);
        k_gnn_att<<<B * (N / 16), 256, 0, stream>>>(h, s1, s2, adjacency, xs);
    }
    k_compound<<<B, 256, 0, stream>>>(xs, fp_mask, Watt, batt, compound, hc);

    // ---- Transformer ----
    k_pe<<<(L * DM + 255) / 256, 256, 0, stream>>>(pe);
    k_embed_word<<<(B * L * DM + 255) / 256, 256, 0, stream>>>(words, emb_word, pe, x);
    k_layernorm<<<B * L, DM, 0, stream>>>(x, ln1_g, ln1_b, xn);
    k_qkv<<<B * L / RF, 3 * DM, 0, stream>>>(xn, Wq, bq, Wk, bk, Wv, bv, qb, kb, vb);
    k_attn<<<B * H * (L / AQR), 512, 0, stream>>>(qb, kb, vb, words_mask, attnout);
    k_oproj<<<B * L / RF, DM, 0, stream>>>(attnout, Wo, bo, x);
    k_layernorm<<<B * L, DM, 0, stream>>>(x, ln2_g, ln2_b, xn);
    k_ffn<<<B * L / RF, DFF, 0, stream>>>(xn, W1, b1, W2, b2, x);
    k_lnf_hp<<<B * L, DM, 0, stream>>>(x, lnf_g, lnf_b, Wtout, btout, Watt, batt, hp);
    k_final<<<B, 256, 0, stream>>>(hp, hc, compound, Wout, bout, Wint, bint, out);
}

// Round 12
// 255.170 us; speedup vs baseline: 1.6715x; 1.6715x over previous
//
#include <hip/hip_runtime.h>
#include <hip/hip_bf16.h>
#include <math.h>

#define B 16
#define N 512
#define L 512
#define DIM 10
#define DM 128
#define H 8
#define DK 16
#define DFF 512
#define LG 3
#define LO 3
#define NEGV -9.0e15f
#define RF 16     // rows per block (ffn/qkv/oproj)
#define AQR 64    // q-rows per attn block

__device__ __forceinline__ float wave_reduce_sum(float v) {
    #pragma unroll
    for (int o = 32; o > 0; o >>= 1) v += __shfl_down(v, o, 64);
    return v;
}

// sum across the 4 lanes of a quad via DPP (VALU pipe, not DS).
// quad_perm[1,0,3,2] = 0xB1 ; quad_perm[2,3,0,1] = 0x4E.
// fp add is commutative -> all 4 lanes end with the bit-identical sum.
__device__ __forceinline__ float quad_sum(float x) {
    int y1 = __builtin_amdgcn_mov_dpp(__float_as_int(x), 0xB1, 0xF, 0xF, true);
    float s = x + __int_as_float(y1);
    int y2 = __builtin_amdgcn_mov_dpp(__float_as_int(s), 0x4E, 0xF, 0xF, true);
    return s + __int_as_float(y2);
}

// ---------------- GNN ----------------

__global__ void k_embed_fp(const int* __restrict__ fing, const float* __restrict__ emb_fp,
                           float* __restrict__ xs) {
    int idx = blockIdx.x * blockDim.x + threadIdx.x;
    if (idx >= B * N * DIM) return;
    int d = idx % DIM;
    int bn = idx / DIM;
    xs[idx] = emb_fp[fing[bn] * DIM + d];
}

__global__ void k_gnn_h(const float* __restrict__ xs, const float* __restrict__ fp_mask,
                        const float* __restrict__ Wg, const float* __restrict__ bg,
                        const float* __restrict__ aatt,
                        float* __restrict__ h, float* __restrict__ s1, float* __restrict__ s2) {
    int bn = blockIdx.x * blockDim.x + threadIdx.x;
    if (bn >= B * N) return;
    float x[DIM];
    #pragma unroll
    for (int d = 0; d < DIM; d++) x[d] = xs[bn * DIM + d];
    float m = fp_mask[bn];
    float a1 = 0.f, a2 = 0.f;
    #pragma unroll
    for (int j = 0; j < DIM; j++) {
        float acc = bg[j];
        #pragma unroll
        for (int d = 0; d < DIM; d++) acc += x[d] * Wg[d * DIM + j];
        acc = fmaxf(acc, 0.f) * m;
        h[bn * DIM + j] = acc;
        a1 += acc * aatt[j];
        a2 += acc * aatt[DIM + j];
    }
    s1[bn] = a1;
    s2[bn] = a2;
}

// 16 lane-groups of 16 lanes; each group owns one row. grid = B*(N/16), 256 thr.
__global__ void k_gnn_att(const float* __restrict__ h, const float* __restrict__ s1,
                          const float* __restrict__ s2, const int* __restrict__ adj,
                          float* __restrict__ xs) {
    int b  = blockIdx.x / (N / 16);
    int rg = blockIdx.x % (N / 16);
    int t = threadIdx.x;
    int g  = t >> 4;   // group 0..15
    int ll = t & 15;   // lane in group
    int i = rg * 16 + g;

    __shared__ float h_s[N * DIM];   // 20KB
    __shared__ float s2_s[N];        // 2KB

    const float* hb = h + (long)b * N * DIM;
    for (int idx = t; idx < N * DIM; idx += 256) h_s[idx] = hb[idx];
    for (int j = t; j < N; j += 256) s2_s[j] = s2[b * N + j];
    __syncthreads();

    float s1v = s1[b * N + i];
    const int* adjrow = adj + ((long)b * N + i) * N;

    float e[32];
    #pragma unroll
    for (int c = 0; c < 32; c++) {
        int j = c * 16 + ll;
        float xsc = s1v + s2_s[j];
        xsc = xsc > 0.f ? xsc : 0.01f * xsc;
        e[c] = (adjrow[j] > 0) ? xsc : NEGV;
    }
    float m = e[0];
    #pragma unroll
    for (int c = 1; c < 32; c++) m = fmaxf(m, e[c]);
    #pragma unroll
    for (int off = 1; off < 16; off <<= 1) m = fmaxf(m, __shfl_xor(m, off, 64));

    float sum = 0.f;
    float a[DIM];
    #pragma unroll
    for (int d = 0; d < DIM; d++) a[d] = 0.f;
    #pragma unroll
    for (int c = 0; c < 32; c++) {
        float p = expf(e[c] - m);
        sum += p;
        int j = c * 16 + ll;
        #pragma unroll
        for (int d = 0; d < DIM; d++) a[d] += p * h_s[j * DIM + d];
    }
    #pragma unroll
    for (int off = 1; off < 16; off <<= 1) {
        sum += __shfl_xor(sum, off, 64);
        #pragma unroll
        for (int d = 0; d < DIM; d++) a[d] += __shfl_xor(a[d], off, 64);
    }
    if (ll < DIM) {
        float av = a[0];
        if (ll == 1) av = a[1]; else if (ll == 2) av = a[2]; else if (ll == 3) av = a[3];
        else if (ll == 4) av = a[4]; else if (ll == 5) av = a[5]; else if (ll == 6) av = a[6];
        else if (ll == 7) av = a[7]; else if (ll == 8) av = a[8]; else if (ll == 9) av = a[9];
        xs[((long)b * N + i) * DIM + ll] += av / sum;
    }
}

__global__ void k_compound(const float* __restrict__ xs, const float* __restrict__ fp_mask,
                           const float* __restrict__ Watt, const float* __restrict__ batt,
                           float* __restrict__ compound, float* __restrict__ hc) {
    int b = blockIdx.x;
    int t = threadIdx.x;  // 256
    int wid = t >> 6, lane = t & 63;
    float lacc[DIM];
    #pragma unroll
    for (int d = 0; d < DIM; d++) lacc[d] = 0.f;
    for (int n = t; n < N; n += 256) {
        float m = fp_mask[b * N + n];
        #pragma unroll
        for (int d = 0; d < DIM; d++) lacc[d] += xs[((long)b * N + n) * DIM + d] * m;
    }
    __shared__ float red[4][DIM];
    __shared__ float comp_s[DIM];
    #pragma unroll
    for (int d = 0; d < DIM; d++) lacc[d] = wave_reduce_sum(lacc[d]);
    if (lane == 0) {
        #pragma unroll
        for (int d = 0; d < DIM; d++) red[wid][d] = lacc[d];
    }
    __syncthreads();
    if (t < DIM) {
        float c = (red[0][t] + red[1][t] + red[2][t] + red[3][t]) / (float)N;
        compound[b * DIM + t] = c;
        comp_s[t] = c;
    }
    __syncthreads();
    if (t < DIM) {
        float acc = batt[t];
        #pragma unroll
        for (int e = 0; e < DIM; e++) acc += comp_s[e] * Watt[e * DIM + t];
        hc[b * DIM + t] = fmaxf(acc, 0.f);
    }
}

// ---------------- Transformer ----------------

__global__ void k_pe(float* __restrict__ pe) {
    int idx = blockIdx.x * blockDim.x + threadIdx.x;
    if (idx >= L * DM) return;
    int d = idx % DM, l = idx / DM;
    int k = d >> 1;
    double div = exp((double)(2 * k) * (-log(10000.0) / (double)DM));
    double ang = (double)l * div;
    pe[idx] = (d & 1) ? (float)cos(ang) : (float)sin(ang);
}

__global__ void k_embed_word(const int* __restrict__ words, const float* __restrict__ emb,
                             const float* __restrict__ pe, float* __restrict__ x) {
    long idx = (long)blockIdx.x * blockDim.x + threadIdx.x;
    if (idx >= (long)B * L * DM) return;
    int d = idx % DM;
    long bl = idx / DM;
    int l = (int)(bl % L);
    x[idx] = emb[(long)words[bl] * DM + d] * sqrtf(128.0f) + pe[l * DM + d];
}

__global__ void k_layernorm(const float* __restrict__ x, const float* __restrict__ g,
                            const float* __restrict__ bb, float* __restrict__ out) {
    int row = blockIdx.x;
    int t = threadIdx.x;  // 128
    int wid = t >> 6, lane = t & 63;
    float v = x[(long)row * DM + t];
    float s = wave_reduce_sum(v);
    __shared__ float r2[2], r3[2];
    if (lane == 0) r2[wid] = s;
    __syncthreads();
    float mean = (r2[0] + r2[1]) / (float)DM;
    float dv = v - mean;
    float q = wave_reduce_sum(dv * dv);
    if (lane == 0) r3[wid] = q;
    __syncthreads();
    float sd = sqrtf((r3[0] + r3[1]) / (float)(DM - 1)) + 1e-6f;
    out[(long)row * DM + t] = g[t] * dv / sd + bb[t];
}

// 16 rows per block, 384 threads: thread = (proj, out-col)
__global__ void k_qkv(const float* __restrict__ xn,
                      const float* __restrict__ Wq, const float* __restrict__ bq,
                      const float* __restrict__ Wk, const float* __restrict__ bk,
                      const float* __restrict__ Wv, const float* __restrict__ bv,
                      float* __restrict__ q, float* __restrict__ k, float* __restrict__ v) {
    long row0 = (long)blockIdx.x * RF;
    int t = threadIdx.x;  // 384
    __shared__ float xs_s[RF * DM];
    for (int i = t; i < RF * DM; i += 384) xs_s[i] = xn[row0 * DM + i];
    __syncthreads();
    int proj = t / DM;
    int j = t % DM;
    const float* W    = proj == 0 ? Wq : (proj == 1 ? Wk : Wv);
    const float* bias = proj == 0 ? bq : (proj == 1 ? bk : bv);
    float* out        = proj == 0 ? q  : (proj == 1 ? k  : v);
    float acc[RF];
    #pragma unroll
    for (int r = 0; r < RF; r++) acc[r] = bias[j];
    for (int d = 0; d < DM; d++) {
        float w = W[d * DM + j];
        #pragma unroll
        for (int r = 0; r < RF; r++) acc[r] += xs_s[r * DM + d] * w;
    }
    #pragma unroll
    for (int r = 0; r < RF; r++) {
        long row = row0 + r;
        int b = (int)(row / L), l = (int)(row % L);
        out[(((long)b * H + j / DK) * L + l) * DK + (j % DK)] = acc[r];
    }
}

// dim-sliced flash attention (round-4 structure, DS-pipe-thinned).
// grid = B*H*(L/AQR), 256 threads: sl = t&3 owns a q/out float4 slice,
// r = t>>2 is the q-row. Per key: 1 ds_read_b128 (K slice) + 2 DPP adds
// (VALU quad-perm, replaces the 2 ds_bpermute shuffles). Mask staged as
// additive 0/-1e9, read as float4 (0.25 DS op/key). V from global
// (64B-line broadcast across the 16 row-lanes, L1/L2-resident).
__global__ void __launch_bounds__(256, 4)
k_attn(const float* __restrict__ q, const float* __restrict__ k,
       const float* __restrict__ v, const float* __restrict__ wmask,
       float* __restrict__ attnout) {
    int blk = blockIdx.x;
    int qc = blk % (L / AQR);
    int bh = blk / (L / AQR);
    int b = bh / H, hh = bh % H;
    int t = threadIdx.x;   // 256
    int sl = t & 3;
    int r = t >> 2;
    int l = qc * AQR + r;

    __shared__ float4 k_s[L * 4];   // 32KB
    __shared__ float wm_s[L];       // 2KB, additive mask 0 / -1e9
    const float4* kb4 = (const float4*)(k + (long)bh * L * DK);
    for (int i = t; i < L * 4; i += 256) k_s[i] = kb4[i];
    for (int j = t; j < L; j += 256) wm_s[j] = (wmask[b * L + j] > 0.f) ? 0.f : -1e9f;
    __syncthreads();

    float4 qr = ((const float4*)(q + ((long)bh * L + l) * DK))[sl];
    qr.x *= 0.25f; qr.y *= 0.25f; qr.z *= 0.25f; qr.w *= 0.25f;

    const float4* vb4 = (const float4*)(v + (long)bh * L * DK);

    float m = -1e30f, ssum = 0.f;
    float4 acc = make_float4(0.f, 0.f, 0.f, 0.f);

    for (int c = 0; c < L / 8; c++) {
        int j0 = c * 8;
        float s8[8];
        // partial dot over this lane's 4 dims, then quad-combine on VALU
        #pragma unroll
        for (int jj = 0; jj < 8; jj++) {
            float4 kk = k_s[(j0 + jj) * 4 + sl];
            float part = qr.x * kk.x + qr.y * kk.y + qr.z * kk.z + qr.w * kk.w;
            s8[jj] = quad_sum(part);
        }
        // additive mask, vectorized (2 b128 reads per 8 keys)
        const float4* mp = (const float4*)&wm_s[j0];
        float4 ma = mp[0], mb = mp[1];
        s8[0] += ma.x; s8[1] += ma.y; s8[2] += ma.z; s8[3] += ma.w;
        s8[4] += mb.x; s8[5] += mb.y; s8[6] += mb.z; s8[7] += mb.w;

        float cm = fmaxf(fmaxf(fmaxf(s8[0], s8[1]), fmaxf(s8[2], s8[3])),
                         fmaxf(fmaxf(s8[4], s8[5]), fmaxf(s8[6], s8[7])));
        float mn = fmaxf(m, cm);
        float scale = __expf(m - mn);
        ssum *= scale;
        acc.x *= scale; acc.y *= scale; acc.z *= scale; acc.w *= scale;
        m = mn;
        #pragma unroll
        for (int jj = 0; jj < 8; jj++) {
            float p = __expf(s8[jj] - m);
            ssum += p;
            float4 vv = vb4[(j0 + jj) * 4 + sl];
            acc.x += p * vv.x; acc.y += p * vv.y; acc.z += p * vv.z; acc.w += p * vv.w;
        }
    }

    float inv = 1.f / ssum;
    float4* outp = (float4*)(attnout + ((long)b * L + l) * DM + hh * DK);
    outp[sl] = make_float4(acc.x * inv, acc.y * inv, acc.z * inv, acc.w * inv);
}

// x += attnout @ Wo + bo ; 16 rows/block, 128 threads
__global__ void k_oproj(const float* __restrict__ attnout, const float* __restrict__ Wo,
                        const float* __restrict__ bo, float* __restrict__ x) {
    long row0 = (long)blockIdx.x * RF;
    int t = threadIdx.x;  // 128
    __shared__ float a_s[RF * DM];
    for (int i = t; i < RF * DM; i += 128) a_s[i] = attnout[row0 * DM + i];
    __syncthreads();
    float acc[RF];
    #pragma unroll
    for (int r = 0; r < RF; r++) acc[r] = bo[t];
    for (int d = 0; d < DM; d++) {
        float w = Wo[d * DM + t];
        #pragma unroll
        for (int r = 0; r < RF; r++) acc[r] += a_s[r * DM + d] * w;
    }
    #pragma unroll
    for (int r = 0; r < RF; r++) x[(row0 + r) * DM + t] += acc[r];
}

// fused FFN: x += relu(xn@W1+b1)@W2+b2 ; 16 rows/block, 512 threads
__global__ void k_ffn(const float* __restrict__ xn, const float* __restrict__ W1,
                      const float* __restrict__ b1, const float* __restrict__ W2,
                      const float* __restrict__ b2, float* __restrict__ x) {
    long row0 = (long)blockIdx.x * RF;
    int t = threadIdx.x;  // 512
    __shared__ float xs_s[RF * DM];    // 8KB
    __shared__ float h_s[RF * DFF];    // 32KB
    for (int i = t; i < RF * DM; i += 512) xs_s[i] = xn[row0 * DM + i];
    __syncthreads();
    {
        float acc[RF];
        #pragma unroll
        for (int r = 0; r < RF; r++) acc[r] = b1[t];
        for (int d = 0; d < DM; d++) {
            float w = W1[d * DFF + t];
            #pragma unroll
            for (int r = 0; r < RF; r++) acc[r] += xs_s[r * DM + d] * w;
        }
        #pragma unroll
        for (int r = 0; r < RF; r++) h_s[r * DFF + t] = fmaxf(acc[r], 0.f);
    }
    __syncthreads();
    int col = t & 127, rq = t >> 7;   // rq uniform per wave
    float acc2[4];
    #pragma unroll
    for (int rr = 0; rr < 4; rr++) acc2[rr] = b2[col];
    for (int f = 0; f < DFF; f++) {
        float w = W2[f * DM + col];
        #pragma unroll
        for (int rr = 0; rr < 4; rr++) acc2[rr] += h_s[(rq * 4 + rr) * DFF + f] * w;
    }
    #pragma unroll
    for (int rr = 0; rr < 4; rr++) x[(row0 + rq * 4 + rr) * DM + col] += acc2[rr];
}

// lnf -> relu -> Wtout -> Watt/relu -> hp ; per row, 128 threads
__global__ void k_lnf_hp(const float* __restrict__ x, const float* __restrict__ g,
                         const float* __restrict__ bb, const float* __restrict__ Wtout,
                         const float* __restrict__ btout, const float* __restrict__ Watt,
                         const float* __restrict__ batt, float* __restrict__ hp) {
    int row = blockIdx.x;
    int t = threadIdx.x;  // 128
    int wid = t >> 6, lane = t & 63;
    float v = x[(long)row * DM + t];
    float s = wave_reduce_sum(v);
    __shared__ float r2[2], r3[2];
    if (lane == 0) r2[wid] = s;
    __syncthreads();
    float mean = (r2[0] + r2[1]) / (float)DM;
    float dv = v - mean;
    float qq = wave_reduce_sum(dv * dv);
    if (lane == 0) r3[wid] = qq;
    __syncthreads();
    float sd = sqrtf((r3[0] + r3[1]) / (float)(DM - 1)) + 1e-6f;
    float xnv = g[t] * dv / sd + bb[t];
    __shared__ float rrelu[DM];
    rrelu[t] = fmaxf(xnv, 0.f);
    __syncthreads();
    __shared__ float wv_s[DIM];
    if (t < DIM) {
        float acc = btout[t];
        for (int d = 0; d < DM; d++) acc += rrelu[d] * Wtout[d * DIM + t];
        wv_s[t] = acc;
    }
    __syncthreads();
    if (t < DIM) {
        float acc = batt[t];
        #pragma unroll
        for (int e = 0; e < DIM; e++) acc += wv_s[e] * Watt[e * DIM + t];
        hp[(long)row * DIM + t] = fmaxf(acc, 0.f);
    }
}

// final: w = tanh(hc . hp_l) ; protein = mean(w * hp) ; 3-layer MLP ; output.
__global__ void k_final(const float* __restrict__ hp, const float* __restrict__ hc,
                        const float* __restrict__ compound, const float* __restrict__ Wout,
                        const float* __restrict__ bout, const float* __restrict__ Wint,
                        const float* __restrict__ bint, float* __restrict__ out) {
    int b = blockIdx.x;
    int t = threadIdx.x;  // 256
    int wid = t >> 6, lane = t & 63;

    __shared__ float wout_s[LO * 2 * DIM * 2 * DIM];  // 1200 floats
    __shared__ float bout_s[LO * 2 * DIM];
    __shared__ float wint_s[2 * DIM * 2];
    __shared__ float bint_s[2];
    __shared__ float hc_s[DIM];
    __shared__ float red[4][DIM];
    __shared__ float cat_s[2 * DIM];
    __shared__ float tmp_s[2 * DIM];

    for (int i = t; i < LO * 2 * DIM * 2 * DIM; i += 256) wout_s[i] = Wout[i];
    for (int i = t; i < LO * 2 * DIM; i += 256) bout_s[i] = bout[i];
    for (int i = t; i < 2 * DIM * 2; i += 256) wint_s[i] = Wint[i];
    if (t < 2) bint_s[t] = bint[t];
    if (t < DIM) hc_s[t] = hc[b * DIM + t];
    __syncthreads();

    float lacc[DIM];
    #pragma unroll
    for (int e = 0; e < DIM; e++) lacc[e] = 0.f;
    for (int l = t; l < L; l += 256) {
        const float* hpl = hp + ((long)b * L + l) * DIM;
        float hv[DIM];
        float dot = 0.f;
        #pragma unroll
        for (int e = 0; e < DIM; e++) { hv[e] = hpl[e]; dot += hc_s[e] * hv[e]; }
        float w = tanhf(dot);
        #pragma unroll
        for (int e = 0; e < DIM; e++) lacc[e] += w * hv[e];
    }
    #pragma unroll
    for (int e = 0; e < DIM; e++) lacc[e] = wave_reduce_sum(lacc[e]);
    if (lane == 0) {
        #pragma unroll
        for (int e = 0; e < DIM; e++) red[wid][e] = lacc[e];
    }
    __syncthreads();
    if (t < DIM) {
        cat_s[t] = compound[b * DIM + t];
        cat_s[DIM + t] = (red[0][t] + red[1][t] + red[2][t] + red[3][t]) / (float)L;
    }
    __syncthreads();

    for (int j = 0; j < LO; j++) {
        float acc = 0.f;
        if (t < 2 * DIM) {
            acc = bout_s[j * 2 * DIM + t];
            #pragma unroll
            for (int e = 0; e < 2 * DIM; e++)
                acc += cat_s[e] * wout_s[j * 2 * DIM * 2 * DIM + e * 2 * DIM + t];
            acc = fmaxf(acc, 0.f);
            tmp_s[t] = acc;
        }
        __syncthreads();
        if (t < 2 * DIM) cat_s[t] = tmp_s[t];
        __syncthreads();
    }
    if (t < 2) {
        float o = bint_s[t];
        #pragma unroll
        for (int e = 0; e < 2 * DIM; e++) o += cat_s[e] * wint_s[e * 2 + t];
        out[b * 2 + t] = o;
    }
}

extern "C" void kernel_launch(void* const* d_in, const int* in_sizes, int n_in,
                              void* d_out, int out_size, void* d_ws, size_t ws_size,
                              hipStream_t stream) {
    (void)in_sizes; (void)n_in; (void)out_size; (void)ws_size;
    const int*   fingerprints = (const int*)d_in[0];
    const float* fp_mask      = (const float*)d_in[1];
    const int*   adjacency    = (const int*)d_in[2];
    const int*   words        = (const int*)d_in[3];
    const float* words_mask   = (const float*)d_in[4];
    const float* emb_fp       = (const float*)d_in[5];
    const float* emb_word     = (const float*)d_in[6];
    const float* Wg   = (const float*)d_in[7];
    const float* bg   = (const float*)d_in[8];
    const float* attn_a = (const float*)d_in[9];
    const float* Wq = (const float*)d_in[10];
    const float* bq = (const float*)d_in[11];
    const float* Wk = (const float*)d_in[12];
    const float* bk = (const float*)d_in[13];
    const float* Wv = (const float*)d_in[14];
    const float* bv = (const float*)d_in[15];
    const float* Wo = (const float*)d_in[16];
    const float* bo = (const float*)d_in[17];
    const float* ln1_g = (const float*)d_in[18];
    const float* ln1_b = (const float*)d_in[19];
    const float* ln2_g = (const float*)d_in[20];
    const float* ln2_b = (const float*)d_in[21];
    const float* lnf_g = (const float*)d_in[22];
    const float* lnf_b = (const float*)d_in[23];
    const float* W1 = (const float*)d_in[24];
    const float* b1 = (const float*)d_in[25];
    const float* W2 = (const float*)d_in[26];
    const float* b2 = (const float*)d_in[27];
    const float* Wtout = (const float*)d_in[28];
    const float* btout = (const float*)d_in[29];
    const float* Watt  = (const float*)d_in[30];
    const float* batt  = (const float*)d_in[31];
    const float* Wout  = (const float*)d_in[32];
    const float* bout  = (const float*)d_in[33];
    const float* Wint  = (const float*)d_in[34];
    const float* bint  = (const float*)d_in[35];
    float* out = (float*)d_out;

    float* w = (float*)d_ws;
    float* xs = w;        w += B * N * DIM;
    float* h  = w;        w += B * N * DIM;
    float* s1 = w;        w += B * N;
    float* s2 = w;        w += B * N;
    float* compound = w;  w += B * DIM;
    float* hc = w;        w += B * DIM;
    float* pe = w;        w += L * DM;
    float* x  = w;        w += (long)B * L * DM;
    float* xn = w;        w += (long)B * L * DM;
    float* qb = w;        w += (long)B * H * L * DK;
    float* kb = w;        w += (long)B * H * L * DK;
    float* vb = w;        w += (long)B * H * L * DK;
    float* attnout = w;   w += (long)B * L * DM;
    float* hp = w;        w += (long)B * L * DIM;

    // ---- GNN ----
    k_embed_fp<<<(B * N * DIM + 255) / 256, 256, 0, stream>>>(fingerprints, emb_fp, xs);
    for (int i = 0; i < LG; i++) {
        k_gnn_h<<<(B * N + 255) / 256, 256, 0, stream>>>(
            xs, fp_mask, Wg + i * DIM * DIM, bg + i * DIM, attn_a + i * 2 * DIM, h, s1, s2);
        k_gnn_att<<<B * (N / 16), 256, 0, stream>>>(h, s1, s2, adjacency, xs);
    }
    k_compound<<<B, 256, 0, stream>>>(xs, fp_mask, Watt, batt, compound, hc);

    // ---- Transformer ----
    k_pe<<<(L * DM + 255) / 256, 256, 0, stream>>>(pe);
    k_embed_word<<<(B * L * DM + 255) / 256, 256, 0, stream>>>(words, emb_word, pe, x);
    k_layernorm<<<B * L, DM, 0, stream>>>(x, ln1_g, ln1_b, xn);
    k_qkv<<<B * L / RF, 3 * DM, 0, stream>>>(xn, Wq, bq, Wk, bk, Wv, bv, qb, kb, vb);
    k_attn<<<B * H * (L / AQR), 256, 0, stream>>>(qb, kb, vb, words_mask, attnout);
    k_oproj<<<B * L / RF, DM, 0, stream>>>(attnout, Wo, bo, x);
    k_layernorm<<<B * L, DM, 0, stream>>>(x, ln2_g, ln2_b, xn);
    k_ffn<<<B * L / RF, DFF, 0, stream>>>(xn, W1, b1, W2, b2, x);
    k_lnf_hp<<<B * L, DM, 0, stream>>>(x, lnf_g, lnf_b, Wtout, btout, Watt, batt, hp);
    k_final<<<B, 256, 0, stream>>>(hp, hc, compound, Wout, bout, Wint, bint, out);
}

// Round 13
// 246.237 us; speedup vs baseline: 1.7322x; 1.0363x over previous
//
#include <hip/hip_runtime.h>
#include <hip/hip_bf16.h>
#include <math.h>

#define B 16
#define N 512
#define L 512
#define DIM 10
#define DM 128
#define H 8
#define DK 16
#define DFF 512
#define LG 3
#define LO 3
#define NEGV -9.0e15f
#define RF 16     // rows per block (ffn/qkv/oproj)
#define AQR 64    // q-rows per attn block

__device__ __forceinline__ float wave_reduce_sum(float v) {
    #pragma unroll
    for (int o = 32; o > 0; o >>= 1) v += __shfl_down(v, o, 64);
    return v;
}

// sum across the 4 lanes of a quad via DPP (VALU pipe, not DS).
__device__ __forceinline__ float quad_sum(float x) {
    int y1 = __builtin_amdgcn_mov_dpp(__float_as_int(x), 0xB1, 0xF, 0xF, true);
    float s = x + __int_as_float(y1);
    int y2 = __builtin_amdgcn_mov_dpp(__float_as_int(s), 0x4E, 0xF, 0xF, true);
    return s + __int_as_float(y2);
}

// 32-lane-group reduce (lanes of one LN row); offsets stay within 32-halves.
__device__ __forceinline__ float half_reduce_sum(float v) {
    #pragma unroll
    for (int o = 16; o > 0; o >>= 1) v += __shfl_xor(v, o, 64);
    return v;
}

// ---------------- GNN ----------------

__global__ void k_embed_fp(const int* __restrict__ fing, const float* __restrict__ emb_fp,
                           float* __restrict__ xs) {
    int idx = blockIdx.x * blockDim.x + threadIdx.x;
    if (idx >= B * N * DIM) return;
    int d = idx % DIM;
    int bn = idx / DIM;
    xs[idx] = emb_fp[fing[bn] * DIM + d];
}

__global__ void k_gnn_h(const float* __restrict__ xs, const float* __restrict__ fp_mask,
                        const float* __restrict__ Wg, const float* __restrict__ bg,
                        const float* __restrict__ aatt,
                        float* __restrict__ h, float* __restrict__ s1, float* __restrict__ s2) {
    int bn = blockIdx.x * blockDim.x + threadIdx.x;
    if (bn >= B * N) return;
    float x[DIM];
    #pragma unroll
    for (int d = 0; d < DIM; d++) x[d] = xs[bn * DIM + d];
    float m = fp_mask[bn];
    float a1 = 0.f, a2 = 0.f;
    #pragma unroll
    for (int j = 0; j < DIM; j++) {
        float acc = bg[j];
        #pragma unroll
        for (int d = 0; d < DIM; d++) acc += x[d] * Wg[d * DIM + j];
        acc = fmaxf(acc, 0.f) * m;
        h[bn * DIM + j] = acc;
        a1 += acc * aatt[j];
        a2 += acc * aatt[DIM + j];
    }
    s1[bn] = a1;
    s2[bn] = a2;
}

// 16 lane-groups of 16 lanes; each group owns one row. grid = B*(N/16), 256 thr.
__global__ void k_gnn_att(const float* __restrict__ h, const float* __restrict__ s1,
                          const float* __restrict__ s2, const int* __restrict__ adj,
                          float* __restrict__ xs) {
    int b  = blockIdx.x / (N / 16);
    int rg = blockIdx.x % (N / 16);
    int t = threadIdx.x;
    int g  = t >> 4;   // group 0..15
    int ll = t & 15;   // lane in group
    int i = rg * 16 + g;

    __shared__ float h_s[N * DIM];   // 20KB
    __shared__ float s2_s[N];        // 2KB

    const float* hb = h + (long)b * N * DIM;
    for (int idx = t; idx < N * DIM; idx += 256) h_s[idx] = hb[idx];
    for (int j = t; j < N; j += 256) s2_s[j] = s2[b * N + j];
    __syncthreads();

    float s1v = s1[b * N + i];
    const int* adjrow = adj + ((long)b * N + i) * N;

    float e[32];
    #pragma unroll
    for (int c = 0; c < 32; c++) {
        int j = c * 16 + ll;
        float xsc = s1v + s2_s[j];
        xsc = xsc > 0.f ? xsc : 0.01f * xsc;
        e[c] = (adjrow[j] > 0) ? xsc : NEGV;
    }
    float m = e[0];
    #pragma unroll
    for (int c = 1; c < 32; c++) m = fmaxf(m, e[c]);
    #pragma unroll
    for (int off = 1; off < 16; off <<= 1) m = fmaxf(m, __shfl_xor(m, off, 64));

    float sum = 0.f;
    float a[DIM];
    #pragma unroll
    for (int d = 0; d < DIM; d++) a[d] = 0.f;
    #pragma unroll
    for (int c = 0; c < 32; c++) {
        float p = expf(e[c] - m);
        sum += p;
        int j = c * 16 + ll;
        #pragma unroll
        for (int d = 0; d < DIM; d++) a[d] += p * h_s[j * DIM + d];
    }
    #pragma unroll
    for (int off = 1; off < 16; off <<= 1) {
        sum += __shfl_xor(sum, off, 64);
        #pragma unroll
        for (int d = 0; d < DIM; d++) a[d] += __shfl_xor(a[d], off, 64);
    }
    if (ll < DIM) {
        float av = a[0];
        if (ll == 1) av = a[1]; else if (ll == 2) av = a[2]; else if (ll == 3) av = a[3];
        else if (ll == 4) av = a[4]; else if (ll == 5) av = a[5]; else if (ll == 6) av = a[6];
        else if (ll == 7) av = a[7]; else if (ll == 8) av = a[8]; else if (ll == 9) av = a[9];
        xs[((long)b * N + i) * DIM + ll] += av / sum;
    }
}

__global__ void k_compound(const float* __restrict__ xs, const float* __restrict__ fp_mask,
                           const float* __restrict__ Watt, const float* __restrict__ batt,
                           float* __restrict__ compound, float* __restrict__ hc) {
    int b = blockIdx.x;
    int t = threadIdx.x;  // 256
    int wid = t >> 6, lane = t & 63;
    float lacc[DIM];
    #pragma unroll
    for (int d = 0; d < DIM; d++) lacc[d] = 0.f;
    for (int n = t; n < N; n += 256) {
        float m = fp_mask[b * N + n];
        #pragma unroll
        for (int d = 0; d < DIM; d++) lacc[d] += xs[((long)b * N + n) * DIM + d] * m;
    }
    __shared__ float red[4][DIM];
    __shared__ float comp_s[DIM];
    #pragma unroll
    for (int d = 0; d < DIM; d++) lacc[d] = wave_reduce_sum(lacc[d]);
    if (lane == 0) {
        #pragma unroll
        for (int d = 0; d < DIM; d++) red[wid][d] = lacc[d];
    }
    __syncthreads();
    if (t < DIM) {
        float c = (red[0][t] + red[1][t] + red[2][t] + red[3][t]) / (float)N;
        compound[b * DIM + t] = c;
        comp_s[t] = c;
    }
    __syncthreads();
    if (t < DIM) {
        float acc = batt[t];
        #pragma unroll
        for (int e = 0; e < DIM; e++) acc += comp_s[e] * Watt[e * DIM + t];
        hc[b * DIM + t] = fmaxf(acc, 0.f);
    }
}

// ---------------- Transformer ----------------

__global__ void k_pe(float* __restrict__ pe) {
    int idx = blockIdx.x * blockDim.x + threadIdx.x;
    if (idx >= L * DM) return;
    int d = idx % DM, l = idx / DM;
    int k = d >> 1;
    double div = exp((double)(2 * k) * (-log(10000.0) / (double)DM));
    double ang = (double)l * div;
    pe[idx] = (d & 1) ? (float)cos(ang) : (float)sin(ang);
}

// embed + LN1 fused: grid B*L, 128 threads
__global__ void k_embed_ln(const int* __restrict__ words, const float* __restrict__ emb,
                           const float* __restrict__ pe, const float* __restrict__ g,
                           const float* __restrict__ bb,
                           float* __restrict__ x, float* __restrict__ xn) {
    int row = blockIdx.x;
    int t = threadIdx.x;  // 128
    int wid = t >> 6, lane = t & 63;
    int l = row % L;
    float v = emb[(long)words[row] * DM + t] * sqrtf(128.0f) + pe[l * DM + t];
    x[(long)row * DM + t] = v;
    float s = wave_reduce_sum(v);
    __shared__ float r2[2], r3[2];
    if (lane == 0) r2[wid] = s;
    __syncthreads();
    float mean = (r2[0] + r2[1]) / (float)DM;
    float dv = v - mean;
    float q = wave_reduce_sum(dv * dv);
    if (lane == 0) r3[wid] = q;
    __syncthreads();
    float sd = sqrtf((r3[0] + r3[1]) / (float)(DM - 1)) + 1e-6f;
    xn[(long)row * DM + t] = g[t] * dv / sd + bb[t];
}

// 16 rows per block, 384 threads: thread = (proj, out-col); float4 LDS reads
__global__ void k_qkv(const float* __restrict__ xn,
                      const float* __restrict__ Wq, const float* __restrict__ bq,
                      const float* __restrict__ Wk, const float* __restrict__ bk,
                      const float* __restrict__ Wv, const float* __restrict__ bv,
                      float* __restrict__ q, float* __restrict__ k, float* __restrict__ v) {
    long row0 = (long)blockIdx.x * RF;
    int t = threadIdx.x;  // 384
    __shared__ float xs_s[RF * DM];
    for (int i = t; i < RF * DM; i += 384) xs_s[i] = xn[row0 * DM + i];
    __syncthreads();
    int proj = t / DM;
    int j = t % DM;
    const float* W    = proj == 0 ? Wq : (proj == 1 ? Wk : Wv);
    const float* bias = proj == 0 ? bq : (proj == 1 ? bk : bv);
    float* out        = proj == 0 ? q  : (proj == 1 ? k  : v);
    float acc[RF];
    #pragma unroll
    for (int r = 0; r < RF; r++) acc[r] = bias[j];
    for (int d4 = 0; d4 < DM / 4; d4++) {
        float w0 = W[(4 * d4 + 0) * DM + j];
        float w1 = W[(4 * d4 + 1) * DM + j];
        float w2 = W[(4 * d4 + 2) * DM + j];
        float w3 = W[(4 * d4 + 3) * DM + j];
        #pragma unroll
        for (int r = 0; r < RF; r++) {
            float4 xv = ((const float4*)&xs_s[r * DM])[d4];
            acc[r] += xv.x * w0 + xv.y * w1 + xv.z * w2 + xv.w * w3;
        }
    }
    #pragma unroll
    for (int r = 0; r < RF; r++) {
        long row = row0 + r;
        int b = (int)(row / L), l = (int)(row % L);
        out[(((long)b * H + j / DK) * L + l) * DK + (j % DK)] = acc[r];
    }
}

// dim-sliced flash attention (round-12 structure, unchanged)
__global__ void __launch_bounds__(256, 4)
k_attn(const float* __restrict__ q, const float* __restrict__ k,
       const float* __restrict__ v, const float* __restrict__ wmask,
       float* __restrict__ attnout) {
    int blk = blockIdx.x;
    int qc = blk % (L / AQR);
    int bh = blk / (L / AQR);
    int b = bh / H, hh = bh % H;
    int t = threadIdx.x;   // 256
    int sl = t & 3;
    int r = t >> 2;
    int l = qc * AQR + r;

    __shared__ float4 k_s[L * 4];   // 32KB
    __shared__ float wm_s[L];       // 2KB, additive mask 0 / -1e9
    const float4* kb4 = (const float4*)(k + (long)bh * L * DK);
    for (int i = t; i < L * 4; i += 256) k_s[i] = kb4[i];
    for (int j = t; j < L; j += 256) wm_s[j] = (wmask[b * L + j] > 0.f) ? 0.f : -1e9f;
    __syncthreads();

    float4 qr = ((const float4*)(q + ((long)bh * L + l) * DK))[sl];
    qr.x *= 0.25f; qr.y *= 0.25f; qr.z *= 0.25f; qr.w *= 0.25f;

    const float4* vb4 = (const float4*)(v + (long)bh * L * DK);

    float m = -1e30f, ssum = 0.f;
    float4 acc = make_float4(0.f, 0.f, 0.f, 0.f);

    for (int c = 0; c < L / 8; c++) {
        int j0 = c * 8;
        float s8[8];
        #pragma unroll
        for (int jj = 0; jj < 8; jj++) {
            float4 kk = k_s[(j0 + jj) * 4 + sl];
            float part = qr.x * kk.x + qr.y * kk.y + qr.z * kk.z + qr.w * kk.w;
            s8[jj] = quad_sum(part);
        }
        const float4* mp = (const float4*)&wm_s[j0];
        float4 ma = mp[0], mb = mp[1];
        s8[0] += ma.x; s8[1] += ma.y; s8[2] += ma.z; s8[3] += ma.w;
        s8[4] += mb.x; s8[5] += mb.y; s8[6] += mb.z; s8[7] += mb.w;

        float cm = fmaxf(fmaxf(fmaxf(s8[0], s8[1]), fmaxf(s8[2], s8[3])),
                         fmaxf(fmaxf(s8[4], s8[5]), fmaxf(s8[6], s8[7])));
        float mn = fmaxf(m, cm);
        float scale = __expf(m - mn);
        ssum *= scale;
        acc.x *= scale; acc.y *= scale; acc.z *= scale; acc.w *= scale;
        m = mn;
        #pragma unroll
        for (int jj = 0; jj < 8; jj++) {
            float p = __expf(s8[jj] - m);
            ssum += p;
            float4 vv = vb4[(j0 + jj) * 4 + sl];
            acc.x += p * vv.x; acc.y += p * vv.y; acc.z += p * vv.z; acc.w += p * vv.w;
        }
    }

    float inv = 1.f / ssum;
    float4* outp = (float4*)(attnout + ((long)b * L + l) * DM + hh * DK);
    outp[sl] = make_float4(acc.x * inv, acc.y * inv, acc.z * inv, acc.w * inv);
}

// x += attnout @ Wo + bo ; 16 rows/block, 128 threads; float4 LDS reads
__global__ void k_oproj(const float* __restrict__ attnout, const float* __restrict__ Wo,
                        const float* __restrict__ bo, float* __restrict__ x) {
    long row0 = (long)blockIdx.x * RF;
    int t = threadIdx.x;  // 128
    __shared__ float a_s[RF * DM];
    for (int i = t; i < RF * DM; i += 128) a_s[i] = attnout[row0 * DM + i];
    __syncthreads();
    float acc[RF];
    #pragma unroll
    for (int r = 0; r < RF; r++) acc[r] = bo[t];
    for (int d4 = 0; d4 < DM / 4; d4++) {
        float w0 = Wo[(4 * d4 + 0) * DM + t];
        float w1 = Wo[(4 * d4 + 1) * DM + t];
        float w2 = Wo[(4 * d4 + 2) * DM + t];
        float w3 = Wo[(4 * d4 + 3) * DM + t];
        #pragma unroll
        for (int r = 0; r < RF; r++) {
            float4 av = ((const float4*)&a_s[r * DM])[d4];
            acc[r] += av.x * w0 + av.y * w1 + av.z * w2 + av.w * w3;
        }
    }
    #pragma unroll
    for (int r = 0; r < RF; r++) x[(row0 + r) * DM + t] += acc[r];
}

// fused tail: LN2 -> FFN -> +x -> LNf -> relu@Wtout -> @Watt/relu -> hp.
// 16 rows/block, 512 threads. x consumed entirely in-LDS.
__global__ void k_ffn_fused(const float* __restrict__ x,
                            const float* __restrict__ ln2_g, const float* __restrict__ ln2_b,
                            const float* __restrict__ W1, const float* __restrict__ b1,
                            const float* __restrict__ W2, const float* __restrict__ b2,
                            const float* __restrict__ lnf_g, const float* __restrict__ lnf_b,
                            const float* __restrict__ Wtout, const float* __restrict__ btout,
                            const float* __restrict__ Watt, const float* __restrict__ batt,
                            float* __restrict__ hp) {
    long row0 = (long)blockIdx.x * RF;
    int t = threadIdx.x;  // 512

    __shared__ float x_s[RF][DM];       // 8 KB
    __shared__ float xn_s[RF][DM];      // 8 KB  (xn, later x_new)
    __shared__ float h_s[RF][DFF];      // 32 KB
    __shared__ float r_s[RF][DM + 4];   // 8.25 KB (lnf relu, padded)
    __shared__ float wt_s[DM * DIM];    // 5 KB
    __shared__ float wa_s[DIM * DIM];
    __shared__ float bt_s[DIM], ba_s[DIM];
    __shared__ float wv_s[RF][DIM];

    // stage x (512 float4 = whole tile) + small weights
    {
        float4 xv = ((const float4*)(x + row0 * DM))[t];
        ((float4*)&x_s[0][0])[t] = xv;
        for (int i = t; i < DM * DIM; i += 512) wt_s[i] = Wtout[i];
        for (int i = t; i < DIM * DIM; i += 512) wa_s[i] = Watt[i];
        if (t < DIM) { bt_s[t] = btout[t]; ba_s[t] = batt[t]; }
    }
    __syncthreads();

    // ---- LN2: 32 threads per row ----
    {
        int row = t >> 5, c = t & 31;
        float4 v = ((const float4*)&x_s[row][0])[c];
        float s = half_reduce_sum(v.x + v.y + v.z + v.w);
        float mean = s / (float)DM;
        float4 dv = make_float4(v.x - mean, v.y - mean, v.z - mean, v.w - mean);
        float q = half_reduce_sum(dv.x * dv.x + dv.y * dv.y + dv.z * dv.z + dv.w * dv.w);
        float sd = sqrtf(q / (float)(DM - 1)) + 1e-6f;
        const float4 g4 = ((const float4*)ln2_g)[c];
        const float4 b4 = ((const float4*)ln2_b)[c];
        ((float4*)&xn_s[row][0])[c] = make_float4(
            g4.x * dv.x / sd + b4.x, g4.y * dv.y / sd + b4.y,
            g4.z * dv.z / sd + b4.z, g4.w * dv.w / sd + b4.w);
    }
    __syncthreads();

    // ---- FFN phase 1: h = relu(xn @ W1 + b1) ----
    {
        float acc[RF];
        #pragma unroll
        for (int r = 0; r < RF; r++) acc[r] = b1[t];
        for (int d4 = 0; d4 < DM / 4; d4++) {
            float w0 = W1[(4 * d4 + 0) * DFF + t];
            float w1 = W1[(4 * d4 + 1) * DFF + t];
            float w2 = W1[(4 * d4 + 2) * DFF + t];
            float w3 = W1[(4 * d4 + 3) * DFF + t];
            #pragma unroll
            for (int r = 0; r < RF; r++) {
                float4 xv = ((const float4*)&xn_s[r][0])[d4];
                acc[r] += xv.x * w0 + xv.y * w1 + xv.z * w2 + xv.w * w3;
            }
        }
        #pragma unroll
        for (int r = 0; r < RF; r++) h_s[r][t] = fmaxf(acc[r], 0.f);
    }
    __syncthreads();

    // ---- FFN phase 2 + residual: x_new = x + h @ W2 + b2 (into xn_s) ----
    {
        int col = t & 127, rq = t >> 7;
        float acc2[4];
        #pragma unroll
        for (int rr = 0; rr < 4; rr++) acc2[rr] = b2[col];
        for (int f4 = 0; f4 < DFF / 4; f4++) {
            float w0 = W2[(4 * f4 + 0) * DM + col];
            float w1 = W2[(4 * f4 + 1) * DM + col];
            float w2 = W2[(4 * f4 + 2) * DM + col];
            float w3 = W2[(4 * f4 + 3) * DM + col];
            #pragma unroll
            for (int rr = 0; rr < 4; rr++) {
                float4 hv = ((const float4*)&h_s[rq * 4 + rr][0])[f4];
                acc2[rr] += hv.x * w0 + hv.y * w1 + hv.z * w2 + hv.w * w3;
            }
        }
        __syncthreads();   // done reading xn_s as LN2 output
        #pragma unroll
        for (int rr = 0; rr < 4; rr++) {
            int row = rq * 4 + rr;
            xn_s[row][col] = x_s[row][col] + acc2[rr];
        }
    }
    __syncthreads();

    // ---- LNf + relu -> r_s ----
    {
        int row = t >> 5, c = t & 31;
        float4 v = ((const float4*)&xn_s[row][0])[c];
        float s = half_reduce_sum(v.x + v.y + v.z + v.w);
        float mean = s / (float)DM;
        float4 dv = make_float4(v.x - mean, v.y - mean, v.z - mean, v.w - mean);
        float q = half_reduce_sum(dv.x * dv.x + dv.y * dv.y + dv.z * dv.z + dv.w * dv.w);
        float sd = sqrtf(q / (float)(DM - 1)) + 1e-6f;
        const float4 g4 = ((const float4*)lnf_g)[c];
        const float4 b4 = ((const float4*)lnf_b)[c];
        r_s[row][4 * c + 0] = fmaxf(g4.x * dv.x / sd + b4.x, 0.f);
        r_s[row][4 * c + 1] = fmaxf(g4.y * dv.y / sd + b4.y, 0.f);
        r_s[row][4 * c + 2] = fmaxf(g4.z * dv.z / sd + b4.z, 0.f);
        r_s[row][4 * c + 3] = fmaxf(g4.w * dv.w / sd + b4.w, 0.f);
    }
    __syncthreads();

    // ---- word_vectors = relu @ Wtout + btout (160 threads) ----
    if (t < RF * DIM) {
        int row = t / DIM, o = t % DIM;
        float acc = bt_s[o];
        for (int d = 0; d < DM; d++) acc += r_s[row][d] * wt_s[d * DIM + o];
        wv_s[row][o] = acc;
    }
    __syncthreads();

    // ---- hp = relu(wv @ Watt + batt) ----
    if (t < RF * DIM) {
        int row = t / DIM, o = t % DIM;
        float acc = ba_s[o];
        #pragma unroll
        for (int e = 0; e < DIM; e++) acc += wv_s[row][e] * wa_s[e * DIM + o];
        hp[(row0 + row) * DIM + o] = fmaxf(acc, 0.f);
    }
}

// final: w = tanh(hc . hp_l) ; protein = mean(w * hp) ; 3-layer MLP ; output.
__global__ void k_final(const float* __restrict__ hp, const float* __restrict__ hc,
                        const float* __restrict__ compound, const float* __restrict__ Wout,
                        const float* __restrict__ bout, const float* __restrict__ Wint,
                        const float* __restrict__ bint, float* __restrict__ out) {
    int b = blockIdx.x;
    int t = threadIdx.x;  // 256
    int wid = t >> 6, lane = t & 63;

    __shared__ float wout_s[LO * 2 * DIM * 2 * DIM];  // 1200 floats
    __shared__ float bout_s[LO * 2 * DIM];
    __shared__ float wint_s[2 * DIM * 2];
    __shared__ float bint_s[2];
    __shared__ float hc_s[DIM];
    __shared__ float red[4][DIM];
    __shared__ float cat_s[2 * DIM];
    __shared__ float tmp_s[2 * DIM];

    for (int i = t; i < LO * 2 * DIM * 2 * DIM; i += 256) wout_s[i] = Wout[i];
    for (int i = t; i < LO * 2 * DIM; i += 256) bout_s[i] = bout[i];
    for (int i = t; i < 2 * DIM * 2; i += 256) wint_s[i] = Wint[i];
    if (t < 2) bint_s[t] = bint[t];
    if (t < DIM) hc_s[t] = hc[b * DIM + t];
    __syncthreads();

    float lacc[DIM];
    #pragma unroll
    for (int e = 0; e < DIM; e++) lacc[e] = 0.f;
    for (int l = t; l < L; l += 256) {
        const float* hpl = hp + ((long)b * L + l) * DIM;
        float hv[DIM];
        float dot = 0.f;
        #pragma unroll
        for (int e = 0; e < DIM; e++) { hv[e] = hpl[e]; dot += hc_s[e] * hv[e]; }
        float w = tanhf(dot);
        #pragma unroll
        for (int e = 0; e < DIM; e++) lacc[e] += w * hv[e];
    }
    #pragma unroll
    for (int e = 0; e < DIM; e++) lacc[e] = wave_reduce_sum(lacc[e]);
    if (lane == 0) {
        #pragma unroll
        for (int e = 0; e < DIM; e++) red[wid][e] = lacc[e];
    }
    __syncthreads();
    if (t < DIM) {
        cat_s[t] = compound[b * DIM + t];
        cat_s[DIM + t] = (red[0][t] + red[1][t] + red[2][t] + red[3][t]) / (float)L;
    }
    __syncthreads();

    for (int j = 0; j < LO; j++) {
        float acc = 0.f;
        if (t < 2 * DIM) {
            acc = bout_s[j * 2 * DIM + t];
            #pragma unroll
            for (int e = 0; e < 2 * DIM; e++)
                acc += cat_s[e] * wout_s[j * 2 * DIM * 2 * DIM + e * 2 * DIM + t];
            acc = fmaxf(acc, 0.f);
            tmp_s[t] = acc;
        }
        __syncthreads();
        if (t < 2 * DIM) cat_s[t] = tmp_s[t];
        __syncthreads();
    }
    if (t < 2) {
        float o = bint_s[t];
        #pragma unroll
        for (int e = 0; e < 2 * DIM; e++) o += cat_s[e] * wint_s[e * 2 + t];
        out[b * 2 + t] = o;
    }
}

extern "C" void kernel_launch(void* const* d_in, const int* in_sizes, int n_in,
                              void* d_out, int out_size, void* d_ws, size_t ws_size,
                              hipStream_t stream) {
    (void)in_sizes; (void)n_in; (void)out_size; (void)ws_size;
    const int*   fingerprints = (const int*)d_in[0];
    const float* fp_mask      = (const float*)d_in[1];
    const int*   adjacency    = (const int*)d_in[2];
    const int*   words        = (const int*)d_in[3];
    const float* words_mask   = (const float*)d_in[4];
    const float* emb_fp       = (const float*)d_in[5];
    const float* emb_word     = (const float*)d_in[6];
    const float* Wg   = (const float*)d_in[7];
    const float* bg   = (const float*)d_in[8];
    const float* attn_a = (const float*)d_in[9];
    const float* Wq = (const float*)d_in[10];
    const float* bq = (const float*)d_in[11];
    const float* Wk = (const float*)d_in[12];
    const float* bk = (const float*)d_in[13];
    const float* Wv = (const float*)d_in[14];
    const float* bv = (const float*)d_in[15];
    const float* Wo = (const float*)d_in[16];
    const float* bo = (const float*)d_in[17];
    const float* ln1_g = (const float*)d_in[18];
    const float* ln1_b = (const float*)d_in[19];
    const float* ln2_g = (const float*)d_in[20];
    const float* ln2_b = (const float*)d_in[21];
    const float* lnf_g = (const float*)d_in[22];
    const float* lnf_b = (const float*)d_in[23];
    const float* W1 = (const float*)d_in[24];
    const float* b1 = (const float*)d_in[25];
    const float* W2 = (const float*)d_in[26];
    const float* b2 = (const float*)d_in[27];
    const float* Wtout = (const float*)d_in[28];
    const float* btout = (const float*)d_in[29];
    const float* Watt  = (const float*)d_in[30];
    const float* batt  = (const float*)d_in[31];
    const float* Wout  = (const float*)d_in[32];
    const float* bout  = (const float*)d_in[33];
    const float* Wint  = (const float*)d_in[34];
    const float* bint  = (const float*)d_in[35];
    float* out = (float*)d_out;

    float* w = (float*)d_ws;
    float* xs = w;        w += B * N * DIM;
    float* h  = w;        w += B * N * DIM;
    float* s1 = w;        w += B * N;
    float* s2 = w;        w += B * N;
    float* compound = w;  w += B * DIM;
    float* hc = w;        w += B * DIM;
    float* pe = w;        w += L * DM;
    float* x  = w;        w += (long)B * L * DM;
    float* xn = w;        w += (long)B * L * DM;
    float* qb = w;        w += (long)B * H * L * DK;
    float* kb = w;        w += (long)B * H * L * DK;
    float* vb = w;        w += (long)B * H * L * DK;
    float* attnout = w;   w += (long)B * L * DM;
    float* hp = w;        w += (long)B * L * DIM;

    // ---- GNN ----
    k_embed_fp<<<(B * N * DIM + 255) / 256, 256, 0, stream>>>(fingerprints, emb_fp, xs);
    for (int i = 0; i < LG; i++) {
        k_gnn_h<<<(B * N + 255) / 256, 256, 0, stream>>>(
            xs, fp_mask, Wg + i * DIM * DIM, bg + i * DIM, attn_a + i * 2 * DIM, h, s1, s2);
        k_gnn_att<<<B * (N / 16), 256, 0, stream>>>(h, s1, s2, adjacency, xs);
    }
    k_compound<<<B, 256, 0, stream>>>(xs, fp_mask, Watt, batt, compound, hc);

    // ---- Transformer ----
    k_pe<<<(L * DM + 255) / 256, 256, 0, stream>>>(pe);
    k_embed_ln<<<B * L, DM, 0, stream>>>(words, emb_word, pe, ln1_g, ln1_b, x, xn);
    k_qkv<<<B * L / RF, 3 * DM, 0, stream>>>(xn, Wq, bq, Wk, bk, Wv, bv, qb, kb, vb);
    k_attn<<<B * H * (L / AQR), 256, 0, stream>>>(qb, kb, vb, words_mask, attnout);
    k_oproj<<<B * L / RF, DM, 0, stream>>>(attnout, Wo, bo, x);
    k_ffn_fused<<<B * L / RF, DFF, 0, stream>>>(x, ln2_g, ln2_b, W1, b1, W2, b2,
                                                lnf_g, lnf_b, Wtout, btout, Watt, batt, hp);
    k_final<<<B, 256, 0, stream>>>(hp, hc, compound, Wout, bout, Wint, bint, out);
}